// Round 13
// baseline (226.229 us; speedup 1.0000x reference)
//
#include <hip/hip_runtime.h>
#include <hip/hip_bf16.h>

#define BB 8
#define SS 2500
#define EE 128
#define FF 128
#define LL 8921

using bf8 = __attribute__((ext_vector_type(8))) short;
using bf4 = __attribute__((ext_vector_type(4))) short;
using f4  = __attribute__((ext_vector_type(4))) float;

__device__ __forceinline__ short f2bf(float f) {
  unsigned u = __builtin_bit_cast(unsigned, f);
  u += 0x7fffu + ((u >> 16) & 1u);
  return (short)(u >> 16);
}

// async global->LDS, 16B per lane; LDS dest is wave-uniform base + lane*16
__device__ __forceinline__ void gll16(const void* g, void* l) {
  __builtin_amdgcn_global_load_lds(
      (const __attribute__((address_space(1))) unsigned int*)g,
      (__attribute__((address_space(3))) unsigned int*)l, 16, 0, 0);
}

// DPP helpers: reduce across the 16-lane group (lane&15) on the VALU pipe (no LDS).
template <int CTRL>
__device__ __forceinline__ float dppmv(float x) {
  int r = __builtin_amdgcn_update_dpp(0, __builtin_bit_cast(int, x), CTRL, 0xF, 0xF, false);
  return __builtin_bit_cast(float, r);
}
__device__ __forceinline__ float rowsum16(float x) {
  x += dppmv<0xB1>(x);    // quad_perm xor1
  x += dppmv<0x4E>(x);    // quad_perm xor2
  x += dppmv<0x124>(x);   // row_ror:4
  x += dppmv<0x128>(x);   // row_ror:8
  return x;
}

// ---------------- prep: embed gather -> bf16, wu -> bf16*log2e, conv w repack ----------------
__global__ void prep_kernel(const int* __restrict__ docs, const int* __restrict__ leaf,
                            const float* __restrict__ embed, const float* __restrict__ wu,
                            const float* __restrict__ w3, const float* __restrict__ w5,
                            const float* __restrict__ w9,
                            short* __restrict__ x_bf, short* __restrict__ wu_bf,
                            short* __restrict__ wpack) {
  const int NX = BB * SS * EE / 8;   // 320000
  const int NU = LL * FF / 8;        // 142736
  const int NW = 17 * FF * EE;       // 278528
  int tid = blockIdx.x * 256 + threadIdx.x;
  if (tid < NX) {
    int base = tid * 8;
    int bs = base >> 7, e0 = base & 127;
    int row = docs[bs];
    const float* p = embed + (row << 7) + e0;
    bf8 o;
#pragma unroll
    for (int i = 0; i < 8; ++i) o[i] = f2bf(p[i]);
    *(bf8*)(x_bf + base) = o;
  } else if (tid < NX + NU) {
    int base = (tid - NX) * 8;
    int l = base >> 7, f0 = base & 127;
    int row = leaf[l];
    const float* p = wu + (row << 7) + f0;
    bf8 o;
#pragma unroll
    for (int i = 0; i < 8; ++i) o[i] = f2bf(p[i] * 1.4426950408889634f);  // pre-scale: exp2 path
    *(bf8*)(wu_bf + base) = o;
  } else if (tid < NX + NU + NW) {
    int i = tid - NX - NU;
    int t = i >> 14, fe = i & 16383;
    const float* w; int K, dk;
    if (t < 3)      { w = w3; K = 3; dk = t; }
    else if (t < 8) { w = w5; K = 5; dk = t - 3; }
    else            { w = w9; K = 9; dk = t - 8; }
    wpack[i] = f2bf(w[fe * K + dk]);
  }
}

// ---------------- conv: 3 kernels + tanh + max, MFMA over (e,tap) ----------------
__global__ __launch_bounds__(256, 2) void conv_kernel(
    const short* __restrict__ x_bf, const short* __restrict__ wpack,
    const float* __restrict__ cb3, const float* __restrict__ cb5, const float* __restrict__ cb9,
    short* __restrict__ wf, short* __restrict__ wfT) {
  __shared__ short xt[72][136];   // s rows (halo 4), e cols; 272B stride
  __shared__ short wt[128][136];  // f rows, e cols
  int b = blockIdx.x;             // b fastest -> XCD-local x_bf/wpack
  int s0 = blockIdx.y * 64;
  int tid = threadIdx.x, wid = tid >> 6, lane = tid & 63, g = lane >> 4, c = lane & 15;

  for (int i = tid; i < 72 * 16; i += 256) {
    int r = i >> 4, c8 = (i & 15) << 3, s = s0 + r - 4;
    bf8 v = {0, 0, 0, 0, 0, 0, 0, 0};
    if (s >= 0 && s < SS) v = *(const bf8*)(x_bf + ((b * SS + s) << 7) + c8);
    *(bf8*)&xt[r][c8] = v;
  }

  bf8 wpre[8];
#pragma unroll
  for (int k = 0; k < 8; ++k) {
    int i = tid + (k << 8); int r = i >> 4, c8 = (i & 15) << 3;
    wpre[k] = *(const bf8*)(wpack + (r << 7) + c8);
  }

  float wfm[8][4];
#pragma unroll
  for (int j = 0; j < 8; ++j)
#pragma unroll
    for (int i = 0; i < 4; ++i) wfm[j][i] = -1e30f;

  int tap = 0;
  for (int kid = 0; kid < 3; ++kid) {
    const float* cb = (kid == 0) ? cb3 : (kid == 1) ? cb5 : cb9;
    const int K = (kid == 0) ? 3 : (kid == 1) ? 5 : 9;
    const int pad = K >> 1;
    f4 acc[8];
#pragma unroll
    for (int j = 0; j < 8; ++j) {
      float bvj = cb[j * 16 + c];
      acc[j] = (f4){bvj, bvj, bvj, bvj};
    }
    for (int dk = 0; dk < K; ++dk, ++tap) {
      __syncthreads();
#pragma unroll
      for (int k = 0; k < 8; ++k) {
        int i = tid + (k << 8); int r = i >> 4, c8 = (i & 15) << 3;
        *(bf8*)&wt[r][c8] = wpre[k];
      }
      if (tap < 16) {
#pragma unroll
        for (int k = 0; k < 8; ++k) {
          int i = tid + (k << 8); int r = i >> 4, c8 = (i & 15) << 3;
          wpre[k] = *(const bf8*)(wpack + (tap + 1) * 16384 + (r << 7) + c8);
        }
      }
      __syncthreads();
      int xr = wid * 16 + c + dk - pad + 4;
      __builtin_amdgcn_s_setprio(1);
#pragma unroll
      for (int ks = 0; ks < 4; ++ks) {
        bf8 a = *(const bf8*)&xt[xr][ks * 32 + g * 8];
#pragma unroll
        for (int j = 0; j < 8; ++j) {
          bf8 bb = *(const bf8*)&wt[j * 16 + c][ks * 32 + g * 8];
          acc[j] = __builtin_amdgcn_mfma_f32_16x16x32_bf16(a, bb, acc[j], 0, 0, 0);
        }
      }
      __builtin_amdgcn_s_setprio(0);
    }
#pragma unroll
    for (int j = 0; j < 8; ++j)
#pragma unroll
      for (int i = 0; i < 4; ++i) wfm[j][i] = fmaxf(wfm[j][i], tanhf(acc[j][i]));
  }

  int sb = s0 + wid * 16 + g * 4;
#pragma unroll
  for (int j = 0; j < 8; ++j) {
    int f = j * 16 + c;
#pragma unroll
    for (int i = 0; i < 4; ++i) {
      int s = sb + i;
      if (s < SS) wf[((b * SS + s) << 7) + f] = f2bf(wfm[j][i]);
    }
    int tbase = (b * 128 + f) * SS + sb;
    if (sb + 3 < SS) {
      bf4 pk;
#pragma unroll
      for (int i = 0; i < 4; ++i) pk[i] = f2bf(wfm[j][i]);
      *(bf4*)(wfT + tbase) = pk;
    } else {
#pragma unroll
      for (int i = 0; i < 4; ++i)
        if (sb + i < SS) wfT[tbase + i] = f2bf(wfm[j][i]);
    }
  }
}

// ---------------- flash attention + fused y: Q=wu*log2e [L,F], K=V=wf [S,F] ----------------
// R12 base (VGPR 84 spill-free, conflicts 0, 3 blocks/CU) + split-drain counted vmcnt:
// raw s_barriers; K[4] then V[4] issued; vmcnt(4)+barrier -> QK runs while V still flies;
// vmcnt(0) after softmax (V drain hidden under ~800cy of QK+softmax). Each wave drains
// lgkmcnt(0) before the top barrier so its reads complete before next-tile DMA can land.
// exp2f (wu pre-scaled by log2e). y fused into the epilogue (ctx still in regs).
__global__ __launch_bounds__(256, 3) void attn_kernel(
    const short* __restrict__ wu_bf, const short* __restrict__ wf, const short* __restrict__ wfT,
    const float* __restrict__ fw, const float* __restrict__ fb,
    float* __restrict__ y, float* __restrict__ ctx) {
  __shared__ short kt[64 * 128];   // K tile [s][f], swizzled
  __shared__ short vt[128 * 64];   // V^T tile [f][s], swizzled
  __shared__ short pt[128][68];    // P rows [l][s], 136B stride
  int b = blockIdx.x;              // b fastest -> per-XCD K/V residency in L2
  int l0 = blockIdx.y * 128;
  int tid = threadIdx.x, wid = tid >> 6, lane = tid & 63, g = lane >> 4, c = lane & 15;

  // staging source precompute (tile-invariant): call k covers linear chunks (k*4+wid)*64+lane
  int k_row[4], k_off[4], v_off[4];
#pragma unroll
  for (int k = 0; k < 4; ++k) {
    int idx = (k * 4 + wid) * 64 + lane;
    int r = idx >> 4, ck = idx & 15;
    k_row[k] = r;
    k_off[k] = (ck ^ (r & 15)) << 3;             // shorts within wf row
    int rv = idx >> 3, cv = idx & 7;
    v_off[k] = (b * 128 + rv) * SS + ((cv ^ (rv & 7)) << 3);  // shorts into wfT (+s0 per tile)
  }
  const short* wfb = wf + b * SS * 128;

  bf8 q[2][4];
#pragma unroll
  for (int ms = 0; ms < 2; ++ms) {
    int l = l0 + wid * 32 + ms * 16 + c;
    if (l >= LL) l = LL - 1;
#pragma unroll
    for (int ks = 0; ks < 4; ++ks)
      q[ms][ks] = *(const bf8*)(wu_bf + (l << 7) + ks * 32 + g * 8);
  }

  float lst[2][4];
  f4 o[2][8];
#pragma unroll
  for (int ms = 0; ms < 2; ++ms) {
#pragma unroll
    for (int i = 0; i < 4; ++i) lst[ms][i] = 0.0f;
#pragma unroll
    for (int n = 0; n < 8; ++n) o[ms][n] = (f4){0.f, 0.f, 0.f, 0.f};
  }

  for (int t = 0; t < 40; ++t) {
    int s0 = t * 64;
    bool full = (s0 + 64 <= SS);
    // top barrier: all waves finished reading tile t-1 (own reads drained first)
    asm volatile("s_waitcnt lgkmcnt(0)" ::: "memory");
    __builtin_amdgcn_s_barrier();
    __builtin_amdgcn_sched_barrier(0);
    // stage K tile first [4] (rows clamped; garbage rows are score-masked)
#pragma unroll
    for (int k = 0; k < 4; ++k) {
      int s = s0 + k_row[k];
      if (s > SS - 1) s = SS - 1;
      gll16(wfb + s * 128 + k_off[k], (char*)kt + (k * 4 + wid) * 1024);
    }
    // then V tile [4] (or tail scalar path)
    if (full) {
#pragma unroll
      for (int k = 0; k < 4; ++k)
        gll16(wfT + v_off[k] + s0, (char*)vt + (k * 4 + wid) * 1024);
    } else {
      for (int idx = tid; idx < 128 * 64; idx += 256) {
        int r = idx >> 6, sl = idx & 63, so = s0 + sl;
        short v = (so < SS) ? wfT[(b * 128 + r) * SS + so] : (short)0;
        vt[(r << 6) + (((sl >> 3) ^ (r & 7)) << 3) + (sl & 7)] = v;
      }
      asm volatile("s_waitcnt lgkmcnt(0)" ::: "memory");  // tail scalar ds_writes visible
    }
    // K ready: drain oldest 4 (K); V keeps flying under QK+softmax
    asm volatile("s_waitcnt vmcnt(4)" ::: "memory");
    __builtin_amdgcn_s_barrier();
    __builtin_amdgcn_sched_barrier(0);

    // QK^T + stateless softmax, j-split: kb loaded once per (jh,ks), shared across ms
    float rs[2][4] = {{0.f, 0.f, 0.f, 0.f}, {0.f, 0.f, 0.f, 0.f}};
#pragma unroll
    for (int jh = 0; jh < 2; ++jh) {
      f4 sc[2][2];
#pragma unroll
      for (int ms = 0; ms < 2; ++ms)
#pragma unroll
        for (int jj = 0; jj < 2; ++jj) sc[ms][jj] = (f4){0.f, 0.f, 0.f, 0.f};
      __builtin_amdgcn_s_setprio(1);
#pragma unroll
      for (int ks = 0; ks < 4; ++ks) {
        int xk = (((ks << 2) | g) ^ c) << 3;
        bf8 kb[2];
#pragma unroll
        for (int jj = 0; jj < 2; ++jj)
          kb[jj] = *(const bf8*)&kt[((jh * 2 + jj) * 16 + c) * 128 + xk];
#pragma unroll
        for (int ms = 0; ms < 2; ++ms)
#pragma unroll
          for (int jj = 0; jj < 2; ++jj)
            sc[ms][jj] = __builtin_amdgcn_mfma_f32_16x16x32_bf16(q[ms][ks], kb[jj], sc[ms][jj], 0, 0, 0);
      }
      __builtin_amdgcn_s_setprio(0);
#pragma unroll
      for (int jj = 0; jj < 2; ++jj) {
        int j = jh * 2 + jj;
        int col = j * 16 + c;
        bool masked = (!full) && (s0 + col >= SS);
#pragma unroll
        for (int ms = 0; ms < 2; ++ms) {
          int rbase = wid * 32 + ms * 16 + g * 4;
#pragma unroll
          for (int i = 0; i < 4; ++i) {
            float p = masked ? 0.0f : exp2f(sc[ms][jj][i]);  // wu pre-scaled: 2^(s*log2e)=e^s
            pt[rbase + i][col] = f2bf(p);  // inline P write (own 32-row strip)
            rs[ms][i] += p;                // unrounded denominator
          }
        }
      }
    }
#pragma unroll
    for (int ms = 0; ms < 2; ++ms)
#pragma unroll
      for (int i = 0; i < 4; ++i) lst[ms][i] += rowsum16(rs[ms][i]);

    // V ready: drain remaining DMA (had QK+softmax to land)
    asm volatile("s_waitcnt vmcnt(0)" ::: "memory");
    __builtin_amdgcn_s_barrier();
    __builtin_amdgcn_sched_barrier(0);
    asm volatile("s_waitcnt lgkmcnt(0)" ::: "memory");  // own pt strip visible
    __builtin_amdgcn_sched_barrier(0);

    // PV: A = P [l][s] (own strip, b64 pairs), B^T = V^T [f][s] (swizzled b128)
    __builtin_amdgcn_s_setprio(1);
#pragma unroll
    for (int ks = 0; ks < 2; ++ks) {
      bf8 pa[2];
#pragma unroll
      for (int ms = 0; ms < 2; ++ms) {
        const short* pp = &pt[wid * 32 + ms * 16 + c][ks * 32 + g * 8];
        bf4 lo = *(const bf4*)pp; bf4 hi = *(const bf4*)(pp + 4);
        pa[ms] = __builtin_shufflevector(lo, hi, 0, 1, 2, 3, 4, 5, 6, 7);
      }
      int xv = (((ks << 2) | g) ^ (c & 7)) << 3;
#pragma unroll
      for (int n = 0; n < 8; ++n) {
        bf8 vb = *(const bf8*)&vt[(n * 16 + c) * 64 + xv];
#pragma unroll
        for (int ms = 0; ms < 2; ++ms)
          o[ms][n] = __builtin_amdgcn_mfma_f32_16x16x32_bf16(pa[ms], vb, o[ms][n], 0, 0, 0);
      }
    }
    __builtin_amdgcn_s_setprio(0);
  }

  // epilogue: normalize, write ctx, and fused y = ctx . fw + fb
#pragma unroll
  for (int ms = 0; ms < 2; ++ms)
#pragma unroll
    for (int i = 0; i < 4; ++i) {
      int l = l0 + wid * 32 + ms * 16 + g * 4 + i;
      if (l < LL) {
        float inv = 1.0f / lst[ms][i];
        int rb = (b * LL + l) << 7;
        float acc = 0.0f;
#pragma unroll
        for (int n = 0; n < 8; ++n) {
          float cv = o[ms][n][i] * inv;
          ctx[rb + n * 16 + c] = cv;
          acc += cv * fw[(l << 7) + n * 16 + c];
        }
        acc = rowsum16(acc);
        if (c == 0) y[b * LL + l] = acc + fb[l];
      }
    }
}

extern "C" void kernel_launch(void* const* d_in, const int* in_sizes, int n_in,
                              void* d_out, int out_size, void* d_ws, size_t ws_size,
                              hipStream_t stream) {
  const int* docs = (const int*)d_in[0];
  const int* leaf = (const int*)d_in[3];
  const float* embed = (const float*)d_in[4];
  const float* wu = (const float*)d_in[5];
  const float* fw = (const float*)d_in[6];
  const float* fb = (const float*)d_in[7];
  const float* w3 = (const float*)d_in[8];
  const float* b3 = (const float*)d_in[9];
  const float* w5 = (const float*)d_in[10];
  const float* b5 = (const float*)d_in[11];
  const float* w9 = (const float*)d_in[12];
  const float* b9 = (const float*)d_in[13];

  char* ws = (char*)d_ws;
  short* x_bf  = (short*)(ws);              // [B][S][E] bf16
  short* wu_bf = (short*)(ws + 5120000);    // [L][F] bf16 (pre-scaled by log2e)
  short* wpack = (short*)(ws + 7403776);    // [17][F][E] bf16
  short* wfp   = (short*)(ws + 7960832);    // [B][S][F] bf16
  short* wfT   = (short*)(ws + 13080832);   // [B][F][S] bf16

  float* y = (float*)d_out;
  float* ctx = (float*)d_out + BB * LL;

  prep_kernel<<<2896, 256, 0, stream>>>(docs, leaf, embed, wu, w3, w5, w9, x_bf, wu_bf, wpack);
  conv_kernel<<<dim3(8, 40), 256, 0, stream>>>(x_bf, wpack, b3, b5, b9, wfp, wfT);
  attn_kernel<<<dim3(8, 70), 256, 0, stream>>>(wu_bf, wfp, wfT, fw, fb, y, ctx);
}

// Round 14
// 223.451 us; speedup vs baseline: 1.0124x; 1.0124x over previous
//
#include <hip/hip_runtime.h>
#include <hip/hip_bf16.h>

#define BB 8
#define SS 2500
#define EE 128
#define FF 128
#define LL 8921

using bf8 = __attribute__((ext_vector_type(8))) short;
using bf4 = __attribute__((ext_vector_type(4))) short;
using f4  = __attribute__((ext_vector_type(4))) float;

__device__ __forceinline__ short f2bf(float f) {
  unsigned u = __builtin_bit_cast(unsigned, f);
  u += 0x7fffu + ((u >> 16) & 1u);
  return (short)(u >> 16);
}

// async global->LDS, 16B per lane; LDS dest is wave-uniform base + lane*16
__device__ __forceinline__ void gll16(const void* g, void* l) {
  __builtin_amdgcn_global_load_lds(
      (const __attribute__((address_space(1))) unsigned int*)g,
      (__attribute__((address_space(3))) unsigned int*)l, 16, 0, 0);
}

// DPP helpers: reduce across the 16-lane group (lane&15) on the VALU pipe (no LDS).
template <int CTRL>
__device__ __forceinline__ float dppmv(float x) {
  int r = __builtin_amdgcn_update_dpp(0, __builtin_bit_cast(int, x), CTRL, 0xF, 0xF, false);
  return __builtin_bit_cast(float, r);
}
__device__ __forceinline__ float rowsum16(float x) {
  x += dppmv<0xB1>(x);    // quad_perm xor1
  x += dppmv<0x4E>(x);    // quad_perm xor2
  x += dppmv<0x124>(x);   // row_ror:4
  x += dppmv<0x128>(x);   // row_ror:8
  return x;
}

// ---------------- prep: embed gather -> bf16, wu -> bf16*log2e, conv w repack ----------------
__global__ void prep_kernel(const int* __restrict__ docs, const int* __restrict__ leaf,
                            const float* __restrict__ embed, const float* __restrict__ wu,
                            const float* __restrict__ w3, const float* __restrict__ w5,
                            const float* __restrict__ w9,
                            short* __restrict__ x_bf, short* __restrict__ wu_bf,
                            short* __restrict__ wpack) {
  const int NX = BB * SS * EE / 8;   // 320000
  const int NU = LL * FF / 8;        // 142736
  const int NW = 17 * FF * EE;       // 278528
  int tid = blockIdx.x * 256 + threadIdx.x;
  if (tid < NX) {
    int base = tid * 8;
    int bs = base >> 7, e0 = base & 127;
    int row = docs[bs];
    const float* p = embed + (row << 7) + e0;
    bf8 o;
#pragma unroll
    for (int i = 0; i < 8; ++i) o[i] = f2bf(p[i]);
    *(bf8*)(x_bf + base) = o;
  } else if (tid < NX + NU) {
    int base = (tid - NX) * 8;
    int l = base >> 7, f0 = base & 127;
    int row = leaf[l];
    const float* p = wu + (row << 7) + f0;
    bf8 o;
#pragma unroll
    for (int i = 0; i < 8; ++i) o[i] = f2bf(p[i] * 1.4426950408889634f);  // pre-scale: exp2 path
    *(bf8*)(wu_bf + base) = o;
  } else if (tid < NX + NU + NW) {
    int i = tid - NX - NU;
    int t = i >> 14, fe = i & 16383;
    const float* w; int K, dk;
    if (t < 3)      { w = w3; K = 3; dk = t; }
    else if (t < 8) { w = w5; K = 5; dk = t - 3; }
    else            { w = w9; K = 9; dk = t - 8; }
    wpack[i] = f2bf(w[fe * K + dk]);
  }
}

// ---------------- conv: 3 kernels + tanh + max, MFMA over (e,tap) ----------------
__global__ __launch_bounds__(256, 2) void conv_kernel(
    const short* __restrict__ x_bf, const short* __restrict__ wpack,
    const float* __restrict__ cb3, const float* __restrict__ cb5, const float* __restrict__ cb9,
    short* __restrict__ wf, short* __restrict__ wfT) {
  __shared__ short xt[72][136];   // s rows (halo 4), e cols; 272B stride
  __shared__ short wt[128][136];  // f rows, e cols
  int b = blockIdx.x;             // b fastest -> XCD-local x_bf/wpack
  int s0 = blockIdx.y * 64;
  int tid = threadIdx.x, wid = tid >> 6, lane = tid & 63, g = lane >> 4, c = lane & 15;

  for (int i = tid; i < 72 * 16; i += 256) {
    int r = i >> 4, c8 = (i & 15) << 3, s = s0 + r - 4;
    bf8 v = {0, 0, 0, 0, 0, 0, 0, 0};
    if (s >= 0 && s < SS) v = *(const bf8*)(x_bf + ((b * SS + s) << 7) + c8);
    *(bf8*)&xt[r][c8] = v;
  }

  bf8 wpre[8];
#pragma unroll
  for (int k = 0; k < 8; ++k) {
    int i = tid + (k << 8); int r = i >> 4, c8 = (i & 15) << 3;
    wpre[k] = *(const bf8*)(wpack + (r << 7) + c8);
  }

  float wfm[8][4];
#pragma unroll
  for (int j = 0; j < 8; ++j)
#pragma unroll
    for (int i = 0; i < 4; ++i) wfm[j][i] = -1e30f;

  int tap = 0;
  for (int kid = 0; kid < 3; ++kid) {
    const float* cb = (kid == 0) ? cb3 : (kid == 1) ? cb5 : cb9;
    const int K = (kid == 0) ? 3 : (kid == 1) ? 5 : 9;
    const int pad = K >> 1;
    f4 acc[8];
#pragma unroll
    for (int j = 0; j < 8; ++j) {
      float bvj = cb[j * 16 + c];
      acc[j] = (f4){bvj, bvj, bvj, bvj};
    }
    for (int dk = 0; dk < K; ++dk, ++tap) {
      __syncthreads();
#pragma unroll
      for (int k = 0; k < 8; ++k) {
        int i = tid + (k << 8); int r = i >> 4, c8 = (i & 15) << 3;
        *(bf8*)&wt[r][c8] = wpre[k];
      }
      if (tap < 16) {
#pragma unroll
        for (int k = 0; k < 8; ++k) {
          int i = tid + (k << 8); int r = i >> 4, c8 = (i & 15) << 3;
          wpre[k] = *(const bf8*)(wpack + (tap + 1) * 16384 + (r << 7) + c8);
        }
      }
      __syncthreads();
      int xr = wid * 16 + c + dk - pad + 4;
      __builtin_amdgcn_s_setprio(1);
#pragma unroll
      for (int ks = 0; ks < 4; ++ks) {
        bf8 a = *(const bf8*)&xt[xr][ks * 32 + g * 8];
#pragma unroll
        for (int j = 0; j < 8; ++j) {
          bf8 bb = *(const bf8*)&wt[j * 16 + c][ks * 32 + g * 8];
          acc[j] = __builtin_amdgcn_mfma_f32_16x16x32_bf16(a, bb, acc[j], 0, 0, 0);
        }
      }
      __builtin_amdgcn_s_setprio(0);
    }
#pragma unroll
    for (int j = 0; j < 8; ++j)
#pragma unroll
      for (int i = 0; i < 4; ++i) wfm[j][i] = fmaxf(wfm[j][i], tanhf(acc[j][i]));
  }

  int sb = s0 + wid * 16 + g * 4;
#pragma unroll
  for (int j = 0; j < 8; ++j) {
    int f = j * 16 + c;
#pragma unroll
    for (int i = 0; i < 4; ++i) {
      int s = sb + i;
      if (s < SS) wf[((b * SS + s) << 7) + f] = f2bf(wfm[j][i]);
    }
    int tbase = (b * 128 + f) * SS + sb;
    if (sb + 3 < SS) {
      bf4 pk;
#pragma unroll
      for (int i = 0; i < 4; ++i) pk[i] = f2bf(wfm[j][i]);
      *(bf4*)(wfT + tbase) = pk;
    } else {
#pragma unroll
      for (int i = 0; i < 4; ++i)
        if (sb + i < SS) wfT[tbase + i] = f2bf(wfm[j][i]);
    }
  }
}

// ---------------- flash attention + fused y: Q=wu*log2e [L,F], K=V=wf [S,F] ----------------
// R12's proven 2-barrier loop (176.8us, VGPR 84 spill-free, conflicts 0, 3 blocks/CU)
// + exp2 softmax (wu pre-scaled) + y fused into epilogue. R13's 3-barrier split-drain
// REGRESSED (-14us): the barrier-free softmax->PV->next-read region is what lets waves
// slip past each other; keep 2 barriers/tile.
__global__ __launch_bounds__(256, 3) void attn_kernel(
    const short* __restrict__ wu_bf, const short* __restrict__ wf, const short* __restrict__ wfT,
    const float* __restrict__ fw, const float* __restrict__ fb,
    float* __restrict__ y, float* __restrict__ ctx) {
  __shared__ short kt[64 * 128];   // K tile [s][f], swizzled
  __shared__ short vt[128 * 64];   // V^T tile [f][s], swizzled
  __shared__ short pt[128][68];    // P rows [l][s], 136B stride
  int b = blockIdx.x;              // b fastest -> per-XCD K/V residency in L2
  int l0 = blockIdx.y * 128;
  int tid = threadIdx.x, wid = tid >> 6, lane = tid & 63, g = lane >> 4, c = lane & 15;

  // staging source precompute (tile-invariant): call k covers linear chunks (k*4+wid)*64+lane
  int k_row[4], k_off[4], v_off[4];
#pragma unroll
  for (int k = 0; k < 4; ++k) {
    int idx = (k * 4 + wid) * 64 + lane;
    int r = idx >> 4, ck = idx & 15;
    k_row[k] = r;
    k_off[k] = (ck ^ (r & 15)) << 3;             // shorts within wf row
    int rv = idx >> 3, cv = idx & 7;
    v_off[k] = (b * 128 + rv) * SS + ((cv ^ (rv & 7)) << 3);  // shorts into wfT (+s0 per tile)
  }
  const short* wfb = wf + b * SS * 128;

  bf8 q[2][4];
#pragma unroll
  for (int ms = 0; ms < 2; ++ms) {
    int l = l0 + wid * 32 + ms * 16 + c;
    if (l >= LL) l = LL - 1;
#pragma unroll
    for (int ks = 0; ks < 4; ++ks)
      q[ms][ks] = *(const bf8*)(wu_bf + (l << 7) + ks * 32 + g * 8);
  }

  float lst[2][4];
  f4 o[2][8];
#pragma unroll
  for (int ms = 0; ms < 2; ++ms) {
#pragma unroll
    for (int i = 0; i < 4; ++i) lst[ms][i] = 0.0f;
#pragma unroll
    for (int n = 0; n < 8; ++n) o[ms][n] = (f4){0.f, 0.f, 0.f, 0.f};
  }

  for (int t = 0; t < 40; ++t) {
    int s0 = t * 64;
    bool full = (s0 + 64 <= SS);
    __syncthreads();  // all waves done reading tile t-1 (drains lgkm+vm)
    // stage K tile (rows clamped; garbage rows are score-masked)
#pragma unroll
    for (int k = 0; k < 4; ++k) {
      int s = s0 + k_row[k];
      if (s > SS - 1) s = SS - 1;
      gll16(wfb + s * 128 + k_off[k], (char*)kt + (k * 4 + wid) * 1024);
    }
    if (full) {
#pragma unroll
      for (int k = 0; k < 4; ++k)
        gll16(wfT + v_off[k] + s0, (char*)vt + (k * 4 + wid) * 1024);
    } else {
      // tail tile: scalar masked V staging through the same swizzle
      for (int idx = tid; idx < 128 * 64; idx += 256) {
        int r = idx >> 6, sl = idx & 63, so = s0 + sl;
        short v = (so < SS) ? wfT[(b * 128 + r) * SS + so] : (short)0;
        vt[(r << 6) + (((sl >> 3) ^ (r & 7)) << 3) + (sl & 7)] = v;
      }
    }
    __syncthreads();  // barrier drain waits vmcnt(0): tile t staged

    // QK^T + stateless softmax, j-split: kb loaded once per (jh,ks), shared across ms
    float rs[2][4] = {{0.f, 0.f, 0.f, 0.f}, {0.f, 0.f, 0.f, 0.f}};
#pragma unroll
    for (int jh = 0; jh < 2; ++jh) {
      f4 sc[2][2];
#pragma unroll
      for (int ms = 0; ms < 2; ++ms)
#pragma unroll
        for (int jj = 0; jj < 2; ++jj) sc[ms][jj] = (f4){0.f, 0.f, 0.f, 0.f};
      __builtin_amdgcn_s_setprio(1);
#pragma unroll
      for (int ks = 0; ks < 4; ++ks) {
        int xk = (((ks << 2) | g) ^ c) << 3;
        bf8 kb[2];
#pragma unroll
        for (int jj = 0; jj < 2; ++jj)
          kb[jj] = *(const bf8*)&kt[((jh * 2 + jj) * 16 + c) * 128 + xk];
#pragma unroll
        for (int ms = 0; ms < 2; ++ms)
#pragma unroll
          for (int jj = 0; jj < 2; ++jj)
            sc[ms][jj] = __builtin_amdgcn_mfma_f32_16x16x32_bf16(q[ms][ks], kb[jj], sc[ms][jj], 0, 0, 0);
      }
      __builtin_amdgcn_s_setprio(0);
#pragma unroll
      for (int jj = 0; jj < 2; ++jj) {
        int j = jh * 2 + jj;
        int col = j * 16 + c;
        bool masked = (!full) && (s0 + col >= SS);
#pragma unroll
        for (int ms = 0; ms < 2; ++ms) {
          int rbase = wid * 32 + ms * 16 + g * 4;
#pragma unroll
          for (int i = 0; i < 4; ++i) {
            float p = masked ? 0.0f : exp2f(sc[ms][jj][i]);  // wu pre-scaled: 2^(s*log2e)=e^s
            pt[rbase + i][col] = f2bf(p);  // inline P write (own 32-row strip)
            rs[ms][i] += p;                // unrounded denominator
          }
        }
      }
    }
#pragma unroll
    for (int ms = 0; ms < 2; ++ms)
#pragma unroll
      for (int i = 0; i < 4; ++i) lst[ms][i] += rowsum16(rs[ms][i]);
    asm volatile("s_waitcnt lgkmcnt(0)" ::: "memory");
    __builtin_amdgcn_sched_barrier(0);

    // PV: A = P [l][s] (own strip, b64 pairs), B^T = V^T [f][s] (swizzled b128)
    __builtin_amdgcn_s_setprio(1);
#pragma unroll
    for (int ks = 0; ks < 2; ++ks) {
      bf8 pa[2];
#pragma unroll
      for (int ms = 0; ms < 2; ++ms) {
        const short* pp = &pt[wid * 32 + ms * 16 + c][ks * 32 + g * 8];
        bf4 lo = *(const bf4*)pp; bf4 hi = *(const bf4*)(pp + 4);
        pa[ms] = __builtin_shufflevector(lo, hi, 0, 1, 2, 3, 4, 5, 6, 7);
      }
      int xv = (((ks << 2) | g) ^ (c & 7)) << 3;
#pragma unroll
      for (int n = 0; n < 8; ++n) {
        bf8 vb = *(const bf8*)&vt[(n * 16 + c) * 64 + xv];
#pragma unroll
        for (int ms = 0; ms < 2; ++ms)
          o[ms][n] = __builtin_amdgcn_mfma_f32_16x16x32_bf16(pa[ms], vb, o[ms][n], 0, 0, 0);
      }
    }
    __builtin_amdgcn_s_setprio(0);
  }

  // epilogue: normalize, write ctx, and fused y = ctx . fw + fb
#pragma unroll
  for (int ms = 0; ms < 2; ++ms)
#pragma unroll
    for (int i = 0; i < 4; ++i) {
      int l = l0 + wid * 32 + ms * 16 + g * 4 + i;
      if (l < LL) {
        float inv = 1.0f / lst[ms][i];
        int rb = (b * LL + l) << 7;
        float acc = 0.0f;
#pragma unroll
        for (int n = 0; n < 8; ++n) {
          float cv = o[ms][n][i] * inv;
          ctx[rb + n * 16 + c] = cv;
          acc += cv * fw[(l << 7) + n * 16 + c];
        }
        acc = rowsum16(acc);
        if (c == 0) y[b * LL + l] = acc + fb[l];
      }
    }
}

extern "C" void kernel_launch(void* const* d_in, const int* in_sizes, int n_in,
                              void* d_out, int out_size, void* d_ws, size_t ws_size,
                              hipStream_t stream) {
  const int* docs = (const int*)d_in[0];
  const int* leaf = (const int*)d_in[3];
  const float* embed = (const float*)d_in[4];
  const float* wu = (const float*)d_in[5];
  const float* fw = (const float*)d_in[6];
  const float* fb = (const float*)d_in[7];
  const float* w3 = (const float*)d_in[8];
  const float* b3 = (const float*)d_in[9];
  const float* w5 = (const float*)d_in[10];
  const float* b5 = (const float*)d_in[11];
  const float* w9 = (const float*)d_in[12];
  const float* b9 = (const float*)d_in[13];

  char* ws = (char*)d_ws;
  short* x_bf  = (short*)(ws);              // [B][S][E] bf16
  short* wu_bf = (short*)(ws + 5120000);    // [L][F] bf16 (pre-scaled by log2e)
  short* wpack = (short*)(ws + 7403776);    // [17][F][E] bf16
  short* wfp   = (short*)(ws + 7960832);    // [B][S][F] bf16
  short* wfT   = (short*)(ws + 13080832);   // [B][F][S] bf16

  float* y = (float*)d_out;
  float* ctx = (float*)d_out + BB * LL;

  prep_kernel<<<2896, 256, 0, stream>>>(docs, leaf, embed, wu, w3, w5, w9, x_bf, wu_bf, wpack);
  conv_kernel<<<dim3(8, 40), 256, 0, stream>>>(x_bf, wpack, b3, b5, b9, wfp, wfT);
  attn_kernel<<<dim3(8, 70), 256, 0, stream>>>(wu_bf, wfp, wfT, fw, fb, y, ctx);
}

// Round 15
// 208.445 us; speedup vs baseline: 1.0853x; 1.0720x over previous
//
#include <hip/hip_runtime.h>
#include <hip/hip_bf16.h>

#define BB 8
#define SS 2500
#define EE 128
#define FF 128
#define LL 8921

using bf8 = __attribute__((ext_vector_type(8))) short;
using bf4 = __attribute__((ext_vector_type(4))) short;
using f4  = __attribute__((ext_vector_type(4))) float;

__device__ __forceinline__ short f2bf(float f) {
  unsigned u = __builtin_bit_cast(unsigned, f);
  u += 0x7fffu + ((u >> 16) & 1u);
  return (short)(u >> 16);
}

// async global->LDS, 16B per lane; LDS dest is wave-uniform base + lane*16
__device__ __forceinline__ void gll16(const void* g, void* l) {
  __builtin_amdgcn_global_load_lds(
      (const __attribute__((address_space(1))) unsigned int*)g,
      (__attribute__((address_space(3))) unsigned int*)l, 16, 0, 0);
}

// DPP helpers: reduce across the 16-lane group (lane&15) on the VALU pipe (no LDS).
template <int CTRL>
__device__ __forceinline__ float dppmv(float x) {
  int r = __builtin_amdgcn_update_dpp(0, __builtin_bit_cast(int, x), CTRL, 0xF, 0xF, false);
  return __builtin_bit_cast(float, r);
}
__device__ __forceinline__ float rowsum16(float x) {
  x += dppmv<0xB1>(x);    // quad_perm xor1
  x += dppmv<0x4E>(x);    // quad_perm xor2
  x += dppmv<0x124>(x);   // row_ror:4
  x += dppmv<0x128>(x);   // row_ror:8
  return x;
}

// ---------------- prep: embed gather -> bf16, wu -> bf16, conv w repack ----------------
__global__ void prep_kernel(const int* __restrict__ docs, const int* __restrict__ leaf,
                            const float* __restrict__ embed, const float* __restrict__ wu,
                            const float* __restrict__ w3, const float* __restrict__ w5,
                            const float* __restrict__ w9,
                            short* __restrict__ x_bf, short* __restrict__ wu_bf,
                            short* __restrict__ wpack) {
  const int NX = BB * SS * EE / 8;   // 320000
  const int NU = LL * FF / 8;        // 142736
  const int NW = 17 * FF * EE;       // 278528
  int tid = blockIdx.x * 256 + threadIdx.x;
  if (tid < NX) {
    int base = tid * 8;
    int bs = base >> 7, e0 = base & 127;
    int row = docs[bs];
    const float* p = embed + (row << 7) + e0;
    bf8 o;
#pragma unroll
    for (int i = 0; i < 8; ++i) o[i] = f2bf(p[i]);
    *(bf8*)(x_bf + base) = o;
  } else if (tid < NX + NU) {
    int base = (tid - NX) * 8;
    int l = base >> 7, f0 = base & 127;
    int row = leaf[l];
    const float* p = wu + (row << 7) + f0;
    bf8 o;
#pragma unroll
    for (int i = 0; i < 8; ++i) o[i] = f2bf(p[i]);
    *(bf8*)(wu_bf + base) = o;
  } else if (tid < NX + NU + NW) {
    int i = tid - NX - NU;
    int t = i >> 14, fe = i & 16383;
    const float* w; int K, dk;
    if (t < 3)      { w = w3; K = 3; dk = t; }
    else if (t < 8) { w = w5; K = 5; dk = t - 3; }
    else            { w = w9; K = 9; dk = t - 8; }
    wpack[i] = f2bf(w[fe * K + dk]);
  }
}

// ---------------- conv: 3 kernels + tanh + max, MFMA over (e,tap) ----------------
__global__ __launch_bounds__(256, 2) void conv_kernel(
    const short* __restrict__ x_bf, const short* __restrict__ wpack,
    const float* __restrict__ cb3, const float* __restrict__ cb5, const float* __restrict__ cb9,
    short* __restrict__ wf, short* __restrict__ wfT) {
  __shared__ short xt[72][136];   // s rows (halo 4), e cols; 272B stride
  __shared__ short wt[128][136];  // f rows, e cols
  int b = blockIdx.x;             // b fastest -> XCD-local x_bf/wpack
  int s0 = blockIdx.y * 64;
  int tid = threadIdx.x, wid = tid >> 6, lane = tid & 63, g = lane >> 4, c = lane & 15;

  for (int i = tid; i < 72 * 16; i += 256) {
    int r = i >> 4, c8 = (i & 15) << 3, s = s0 + r - 4;
    bf8 v = {0, 0, 0, 0, 0, 0, 0, 0};
    if (s >= 0 && s < SS) v = *(const bf8*)(x_bf + ((b * SS + s) << 7) + c8);
    *(bf8*)&xt[r][c8] = v;
  }

  bf8 wpre[8];
#pragma unroll
  for (int k = 0; k < 8; ++k) {
    int i = tid + (k << 8); int r = i >> 4, c8 = (i & 15) << 3;
    wpre[k] = *(const bf8*)(wpack + (r << 7) + c8);
  }

  float wfm[8][4];
#pragma unroll
  for (int j = 0; j < 8; ++j)
#pragma unroll
    for (int i = 0; i < 4; ++i) wfm[j][i] = -1e30f;

  int tap = 0;
  for (int kid = 0; kid < 3; ++kid) {
    const float* cb = (kid == 0) ? cb3 : (kid == 1) ? cb5 : cb9;
    const int K = (kid == 0) ? 3 : (kid == 1) ? 5 : 9;
    const int pad = K >> 1;
    f4 acc[8];
#pragma unroll
    for (int j = 0; j < 8; ++j) {
      float bvj = cb[j * 16 + c];
      acc[j] = (f4){bvj, bvj, bvj, bvj};
    }
    for (int dk = 0; dk < K; ++dk, ++tap) {
      __syncthreads();
#pragma unroll
      for (int k = 0; k < 8; ++k) {
        int i = tid + (k << 8); int r = i >> 4, c8 = (i & 15) << 3;
        *(bf8*)&wt[r][c8] = wpre[k];
      }
      if (tap < 16) {
#pragma unroll
        for (int k = 0; k < 8; ++k) {
          int i = tid + (k << 8); int r = i >> 4, c8 = (i & 15) << 3;
          wpre[k] = *(const bf8*)(wpack + (tap + 1) * 16384 + (r << 7) + c8);
        }
      }
      __syncthreads();
      int xr = wid * 16 + c + dk - pad + 4;
      __builtin_amdgcn_s_setprio(1);
#pragma unroll
      for (int ks = 0; ks < 4; ++ks) {
        bf8 a = *(const bf8*)&xt[xr][ks * 32 + g * 8];
#pragma unroll
        for (int j = 0; j < 8; ++j) {
          bf8 bb = *(const bf8*)&wt[j * 16 + c][ks * 32 + g * 8];
          acc[j] = __builtin_amdgcn_mfma_f32_16x16x32_bf16(a, bb, acc[j], 0, 0, 0);
        }
      }
      __builtin_amdgcn_s_setprio(0);
    }
#pragma unroll
    for (int j = 0; j < 8; ++j)
#pragma unroll
      for (int i = 0; i < 4; ++i) wfm[j][i] = fmaxf(wfm[j][i], tanhf(acc[j][i]));
  }

  int sb = s0 + wid * 16 + g * 4;
#pragma unroll
  for (int j = 0; j < 8; ++j) {
    int f = j * 16 + c;
#pragma unroll
    for (int i = 0; i < 4; ++i) {
      int s = sb + i;
      if (s < SS) wf[((b * SS + s) << 7) + f] = f2bf(wfm[j][i]);
    }
    int tbase = (b * 128 + f) * SS + sb;
    if (sb + 3 < SS) {
      bf4 pk;
#pragma unroll
      for (int i = 0; i < 4; ++i) pk[i] = f2bf(wfm[j][i]);
      *(bf4*)(wfT + tbase) = pk;
    } else {
#pragma unroll
      for (int i = 0; i < 4; ++i)
        if (sb + i < SS) wfT[tbase + i] = f2bf(wfm[j][i]);
    }
  }
}

// ---------------- flash attention + fused y: Q=wu [L,F], K=V=wf [S,F] ----------------
// EXACT R12 loop body (176.8us attn proven: __expf, 2-barrier, j-split, VGPR 84
// spill-free, conflicts 0, 3 blocks/CU) + ONLY the fused-y epilogue added.
// R13/R14 isolation: 3-barrier vs 2-barrier was Δ≈0; the +24us regression tracked the
// exp2f path (suspected libcall + caller-save spills: WRITE +5.9MB, FETCH +19MB).
// exp2/prescale REVERTED to __expf (proven inline v_mul+v_exp).
__global__ __launch_bounds__(256, 3) void attn_kernel(
    const short* __restrict__ wu_bf, const short* __restrict__ wf, const short* __restrict__ wfT,
    const float* __restrict__ fw, const float* __restrict__ fb,
    float* __restrict__ y, float* __restrict__ ctx) {
  __shared__ short kt[64 * 128];   // K tile [s][f], swizzled
  __shared__ short vt[128 * 64];   // V^T tile [f][s], swizzled
  __shared__ short pt[128][68];    // P rows [l][s], 136B stride
  int b = blockIdx.x;              // b fastest -> per-XCD K/V residency in L2
  int l0 = blockIdx.y * 128;
  int tid = threadIdx.x, wid = tid >> 6, lane = tid & 63, g = lane >> 4, c = lane & 15;

  // staging source precompute (tile-invariant): call k covers linear chunks (k*4+wid)*64+lane
  int k_row[4], k_off[4], v_off[4];
#pragma unroll
  for (int k = 0; k < 4; ++k) {
    int idx = (k * 4 + wid) * 64 + lane;
    int r = idx >> 4, ck = idx & 15;
    k_row[k] = r;
    k_off[k] = (ck ^ (r & 15)) << 3;             // shorts within wf row
    int rv = idx >> 3, cv = idx & 7;
    v_off[k] = (b * 128 + rv) * SS + ((cv ^ (rv & 7)) << 3);  // shorts into wfT (+s0 per tile)
  }
  const short* wfb = wf + b * SS * 128;

  bf8 q[2][4];
#pragma unroll
  for (int ms = 0; ms < 2; ++ms) {
    int l = l0 + wid * 32 + ms * 16 + c;
    if (l >= LL) l = LL - 1;
#pragma unroll
    for (int ks = 0; ks < 4; ++ks)
      q[ms][ks] = *(const bf8*)(wu_bf + (l << 7) + ks * 32 + g * 8);
  }

  float lst[2][4];
  f4 o[2][8];
#pragma unroll
  for (int ms = 0; ms < 2; ++ms) {
#pragma unroll
    for (int i = 0; i < 4; ++i) lst[ms][i] = 0.0f;
#pragma unroll
    for (int n = 0; n < 8; ++n) o[ms][n] = (f4){0.f, 0.f, 0.f, 0.f};
  }

  for (int t = 0; t < 40; ++t) {
    int s0 = t * 64;
    bool full = (s0 + 64 <= SS);
    __syncthreads();  // all waves done reading tile t-1 (drains lgkm+vm)
    // stage K tile (rows clamped; garbage rows are score-masked)
#pragma unroll
    for (int k = 0; k < 4; ++k) {
      int s = s0 + k_row[k];
      if (s > SS - 1) s = SS - 1;
      gll16(wfb + s * 128 + k_off[k], (char*)kt + (k * 4 + wid) * 1024);
    }
    if (full) {
#pragma unroll
      for (int k = 0; k < 4; ++k)
        gll16(wfT + v_off[k] + s0, (char*)vt + (k * 4 + wid) * 1024);
    } else {
      // tail tile: scalar masked V staging through the same swizzle
      for (int idx = tid; idx < 128 * 64; idx += 256) {
        int r = idx >> 6, sl = idx & 63, so = s0 + sl;
        short v = (so < SS) ? wfT[(b * 128 + r) * SS + so] : (short)0;
        vt[(r << 6) + (((sl >> 3) ^ (r & 7)) << 3) + (sl & 7)] = v;
      }
    }
    __syncthreads();  // barrier drain waits vmcnt(0): tile t staged

    // QK^T + stateless softmax, j-split: kb loaded once per (jh,ks), shared across ms
    float rs[2][4] = {{0.f, 0.f, 0.f, 0.f}, {0.f, 0.f, 0.f, 0.f}};
#pragma unroll
    for (int jh = 0; jh < 2; ++jh) {
      f4 sc[2][2];
#pragma unroll
      for (int ms = 0; ms < 2; ++ms)
#pragma unroll
        for (int jj = 0; jj < 2; ++jj) sc[ms][jj] = (f4){0.f, 0.f, 0.f, 0.f};
      __builtin_amdgcn_s_setprio(1);
#pragma unroll
      for (int ks = 0; ks < 4; ++ks) {
        int xk = (((ks << 2) | g) ^ c) << 3;
        bf8 kb[2];
#pragma unroll
        for (int jj = 0; jj < 2; ++jj)
          kb[jj] = *(const bf8*)&kt[((jh * 2 + jj) * 16 + c) * 128 + xk];
#pragma unroll
        for (int ms = 0; ms < 2; ++ms)
#pragma unroll
          for (int jj = 0; jj < 2; ++jj)
            sc[ms][jj] = __builtin_amdgcn_mfma_f32_16x16x32_bf16(q[ms][ks], kb[jj], sc[ms][jj], 0, 0, 0);
      }
      __builtin_amdgcn_s_setprio(0);
#pragma unroll
      for (int jj = 0; jj < 2; ++jj) {
        int j = jh * 2 + jj;
        int col = j * 16 + c;
        bool masked = (!full) && (s0 + col >= SS);
#pragma unroll
        for (int ms = 0; ms < 2; ++ms) {
          int rbase = wid * 32 + ms * 16 + g * 4;
#pragma unroll
          for (int i = 0; i < 4; ++i) {
            float p = masked ? 0.0f : __expf(sc[ms][jj][i]);  // bounded: exp(|s|<=6.4)
            pt[rbase + i][col] = f2bf(p);  // inline P write (own 32-row strip)
            rs[ms][i] += p;                // unrounded denominator
          }
        }
      }
    }
#pragma unroll
    for (int ms = 0; ms < 2; ++ms)
#pragma unroll
      for (int i = 0; i < 4; ++i) lst[ms][i] += rowsum16(rs[ms][i]);
    asm volatile("s_waitcnt lgkmcnt(0)" ::: "memory");
    __builtin_amdgcn_sched_barrier(0);

    // PV: A = P [l][s] (own strip, b64 pairs), B^T = V^T [f][s] (swizzled b128)
    __builtin_amdgcn_s_setprio(1);
#pragma unroll
    for (int ks = 0; ks < 2; ++ks) {
      bf8 pa[2];
#pragma unroll
      for (int ms = 0; ms < 2; ++ms) {
        const short* pp = &pt[wid * 32 + ms * 16 + c][ks * 32 + g * 8];
        bf4 lo = *(const bf4*)pp; bf4 hi = *(const bf4*)(pp + 4);
        pa[ms] = __builtin_shufflevector(lo, hi, 0, 1, 2, 3, 4, 5, 6, 7);
      }
      int xv = (((ks << 2) | g) ^ (c & 7)) << 3;
#pragma unroll
      for (int n = 0; n < 8; ++n) {
        bf8 vb = *(const bf8*)&vt[(n * 16 + c) * 64 + xv];
#pragma unroll
        for (int ms = 0; ms < 2; ++ms)
          o[ms][n] = __builtin_amdgcn_mfma_f32_16x16x32_bf16(pa[ms], vb, o[ms][n], 0, 0, 0);
      }
    }
    __builtin_amdgcn_s_setprio(0);
  }

  // epilogue: normalize, write ctx, and fused y = ctx . fw + fb
#pragma unroll
  for (int ms = 0; ms < 2; ++ms)
#pragma unroll
    for (int i = 0; i < 4; ++i) {
      int l = l0 + wid * 32 + ms * 16 + g * 4 + i;
      if (l < LL) {
        float inv = 1.0f / lst[ms][i];
        int rb = (b * LL + l) << 7;
        float acc = 0.0f;
#pragma unroll
        for (int n = 0; n < 8; ++n) {
          float cv = o[ms][n][i] * inv;
          ctx[rb + n * 16 + c] = cv;
          acc += cv * fw[(l << 7) + n * 16 + c];
        }
        acc = rowsum16(acc);
        if (c == 0) y[b * LL + l] = acc + fb[l];
      }
    }
}

extern "C" void kernel_launch(void* const* d_in, const int* in_sizes, int n_in,
                              void* d_out, int out_size, void* d_ws, size_t ws_size,
                              hipStream_t stream) {
  const int* docs = (const int*)d_in[0];
  const int* leaf = (const int*)d_in[3];
  const float* embed = (const float*)d_in[4];
  const float* wu = (const float*)d_in[5];
  const float* fw = (const float*)d_in[6];
  const float* fb = (const float*)d_in[7];
  const float* w3 = (const float*)d_in[8];
  const float* b3 = (const float*)d_in[9];
  const float* w5 = (const float*)d_in[10];
  const float* b5 = (const float*)d_in[11];
  const float* w9 = (const float*)d_in[12];
  const float* b9 = (const float*)d_in[13];

  char* ws = (char*)d_ws;
  short* x_bf  = (short*)(ws);              // [B][S][E] bf16
  short* wu_bf = (short*)(ws + 5120000);    // [L][F] bf16
  short* wpack = (short*)(ws + 7403776);    // [17][F][E] bf16
  short* wfp   = (short*)(ws + 7960832);    // [B][S][F] bf16
  short* wfT   = (short*)(ws + 13080832);   // [B][F][S] bf16

  float* y = (float*)d_out;
  float* ctx = (float*)d_out + BB * LL;

  prep_kernel<<<2896, 256, 0, stream>>>(docs, leaf, embed, wu, w3, w5, w9, x_bf, wu_bf, wpack);
  conv_kernel<<<dim3(8, 40), 256, 0, stream>>>(x_bf, wpack, b3, b5, b9, wfp, wfT);
  attn_kernel<<<dim3(8, 70), 256, 0, stream>>>(wu_bf, wfp, wfT, fw, fb, y, ctx);
}